// Round 18
// baseline (2687.694 us; speedup 1.0000x reference)
//
#include <hip/hip_runtime.h>
#include <cmath>

typedef short bs8 __attribute__((ext_vector_type(8)));
typedef float f32x4 __attribute__((ext_vector_type(4)));
typedef __attribute__((address_space(3))) unsigned lds_uint;
typedef __attribute__((address_space(1))) const unsigned gbl_uint;

#define NV 32000
#define SLOTH (32 * 1024)

__device__ __forceinline__ float b2f(unsigned short u) {
  union { unsigned int i; float f; } v; v.i = ((unsigned int)u) << 16; return v.f;
}
__device__ __forceinline__ unsigned short f2b(float f) {
  unsigned int u = __float_as_uint(f);
  return (unsigned short)((u + 0x7FFFu + ((u >> 16) & 1u)) >> 16);
}
__device__ __forceinline__ f32x4 mfma16(bs8 a, bs8 b, f32x4 c) {
  return __builtin_amdgcn_mfma_f32_16x16x32_bf16(a, b, c, 0, 0, 0);
}

// ---- per-producer step-valued flag slots (NO RMW; 16B-spaced) -------------
__device__ __forceinline__ void waitN(const unsigned* slots, int n, unsigned target) {
  if (threadIdx.x < 64) {
    for (;;) {
      unsigned mn = 0xffffffffu;
      for (int i = threadIdx.x; i < n; i += 64) {
        unsigned v = __hip_atomic_load(slots + (size_t)i * 4,
                                       __ATOMIC_RELAXED, __HIP_MEMORY_SCOPE_AGENT);
        mn = mn < v ? mn : v;
      }
#pragma unroll
      for (int off = 32; off; off >>= 1) {
        unsigned o = __shfl_xor(mn, off);
        mn = mn < o ? mn : o;
      }
      if (mn >= target) break;
      __builtin_amdgcn_s_sleep(2);
    }
  }
  __syncthreads();
}
__device__ __forceinline__ void signal_slot(unsigned* slot, unsigned val) {
  __syncthreads();   // full vmcnt drain: data stores globally visible first
  if (threadIdx.x == 0)
    __hip_atomic_store(slot, val, __ATOMIC_RELAXED, __HIP_MEMORY_SCOPE_AGENT);
}

// ---- 4-wave LDS-weight MFMA (R12/R13-proven) ------------------------------
__device__ __forceinline__ void mfma_half_lds(
    const unsigned short* __restrict__ A, const unsigned short* wl,
    f32x4& acc0, f32x4& acc1) {
  int tid = threadIdx.x;
  int w = tid >> 6, l = tid & 63;
  int col = l & 15;
  int kb = w * 256 + (l >> 4) * 8;
  const unsigned short* ap = A + (size_t)col * 1024 + kb;
  const unsigned short* wp = wl + col * 1032 + kb;
#pragma unroll
  for (int kk = 0; kk < 256; kk += 32) {
    bs8 b1 = *(const bs8*)(wp + kk);
    acc0 = mfma16(*(const bs8*)(ap + kk), b1, acc0);
    acc1 = mfma16(*(const bs8*)(ap + 16 * 1024 + kk), b1, acc1);
  }
}
// ---- 4-wave GLOBAL-weight MFMA (weights streamed from L2) -----------------
__device__ __forceinline__ void mfma_half_glb(
    const unsigned short* __restrict__ A, const unsigned short* __restrict__ Wg,
    int u0, f32x4& acc0, f32x4& acc1) {
  int tid = threadIdx.x;
  int w = tid >> 6, l = tid & 63;
  int col = l & 15;
  int kb = w * 256 + (l >> 4) * 8;
  size_t wrow = (size_t)(col >> 2) * 1024 + u0 + (col & 3);
  const unsigned short* ap = A + (size_t)col * 1024 + kb;
  const unsigned short* wp = Wg + wrow * 1024 + kb;
#pragma unroll
  for (int kk = 0; kk < 256; kk += 32) {
    bs8 b1 = *(const bs8*)(wp + kk);
    acc0 = mfma16(*(const bs8*)(ap + kk), b1, acc0);
    acc1 = mfma16(*(const bs8*)(ap + 16 * 1024 + kk), b1, acc1);
  }
}
__device__ __forceinline__ void red_write4(f32x4 acc0, f32x4 acc1, float (*red)[32][17]) {
  int tid = threadIdx.x;
  int w = tid >> 6, l = tid & 63, col = l & 15;
#pragma unroll
  for (int r = 0; r < 4; r++) {
    red[w][(l >> 4) * 4 + r][col] = acc0[r];
    red[w][16 + (l >> 4) * 4 + r][col] = acc1[r];
  }
  __syncthreads();
}
// ---- cell finish (NW-way reduce; h-out atomic write-through) --------------
template <int NW>
__device__ __forceinline__ void cell_finishN(
    int u0, float (*red)[32][17],
    const float* __restrict__ gxrow, const float* __restrict__ bias,
    const float* __restrict__ cprev,
    unsigned short* __restrict__ hout, float* __restrict__ cout) {
  int tid = threadIdx.x;
  if (tid < 128) {
    int b_ = tid >> 2, ul = tid & 3, u = u0 + ul;
    float s0 = 0.f, s1 = 0.f, s2 = 0.f, s3 = 0.f;
#pragma unroll
    for (int ww = 0; ww < NW; ww++) {
      s0 += red[ww][b_][ul];      s1 += red[ww][b_][4 + ul];
      s2 += red[ww][b_][8 + ul];  s3 += red[ww][b_][12 + ul];
    }
    if (gxrow) {
      const float* gp = gxrow + (size_t)b_ * 4096 + u;
      s0 += gp[0]; s1 += gp[1024]; s2 += gp[2048]; s3 += gp[3072];
    }
    if (bias) {
      s0 += bias[u]; s1 += bias[u + 1024]; s2 += bias[u + 2048]; s3 += bias[u + 3072];
    }
    float si = 1.f / (1.f + expf(-s0));
    float sf = 1.f / (1.f + expf(-s1));
    float tg = tanhf(s2);
    float so = 1.f / (1.f + expf(-s3));
    float cn = sf * cprev[b_ * 1024 + u] + si * tg;
    float hn = so * tanhf(cn);
    cout[b_ * 1024 + u] = cn;
    unsigned hv = (unsigned)f2b(hn);
    unsigned ho = __shfl_down(hv, 1);
    if (!(ul & 1)) {
      unsigned packed = hv | (ho << 16);
      __hip_atomic_store((unsigned*)hout + ((size_t)b_ * 512 + (u0 >> 1) + (ul >> 1)),
                         packed, __ATOMIC_RELAXED, __HIP_MEMORY_SCOPE_AGENT);
    }
  }
}

// ================= persistent encoder (R15-PROVEN, unchanged) ==============
__global__ __launch_bounds__(256, 2) void enc_persist(
    const unsigned short* __restrict__ wH0, const float* __restrict__ gx0,
    unsigned short* __restrict__ y0h, float* __restrict__ c0h,
    const unsigned short* __restrict__ wE1, const unsigned short* __restrict__ wH1,
    const float* __restrict__ eb1,
    unsigned short* __restrict__ y1h, float* __restrict__ c1h,
    unsigned* __restrict__ fE, unsigned* __restrict__ fF) {
  __shared__ unsigned short wl[2][16 * 1032];
  __shared__ float red[4][32][17];
  int bid = blockIdx.x, tid = threadIdx.x;
  int lay0 = (bid < 256);
  int u0 = (bid & 255) * 4;
  {
    const unsigned short* W0 = lay0 ? wH0 : wE1;
    const unsigned short* W1 = lay0 ? wH0 : wH1;
    for (int i = tid; i < 2048; i += 256) {
      int c = i >> 7, c8 = (i & 127) * 8;
      size_t grow = (size_t)(c >> 2) * 1024 + u0 + (c & 3);
      *(bs8*)&wl[0][c * 1032 + c8] = *(const bs8*)(W0 + grow * 1024 + c8);
      *(bs8*)&wl[1][c * 1032 + c8] = *(const bs8*)(W1 + grow * 1024 + c8);
    }
    __syncthreads();
  }
  if (lay0) {
    for (int d = 0; d < 64; d++) {
      if (d > 0) waitN(fE, 256, (unsigned)d);
      f32x4 a0 = {0.f, 0.f, 0.f, 0.f}, a1 = {0.f, 0.f, 0.f, 0.f};
      mfma_half_lds(y0h + (size_t)d * SLOTH, wl[0], a0, a1);
      red_write4(a0, a1, red);
      cell_finishN<4>(u0, red, gx0 + (size_t)d * 131072, nullptr,
                      c0h + (size_t)d * SLOTH,
                      y0h + (size_t)(d + 1) * SLOTH, c0h + (size_t)(d + 1) * SLOTH);
      signal_slot(fE + (size_t)bid * 4, (unsigned)(d + 1));
    }
  } else {
    for (int j = 0; j < 64; j++) {
      waitN(fE, 256, (unsigned)(j + 1));
      if (j > 0) waitN(fF, 256, (unsigned)j);
      f32x4 a0 = {0.f, 0.f, 0.f, 0.f}, a1 = {0.f, 0.f, 0.f, 0.f};
      mfma_half_lds(y0h + (size_t)(j + 1) * SLOTH, wl[0], a0, a1);
      mfma_half_lds(y1h + (size_t)j * SLOTH, wl[1], a0, a1);
      red_write4(a0, a1, red);
      cell_finishN<4>(u0, red, nullptr, eb1, c1h + (size_t)j * SLOTH,
                      y1h + (size_t)(j + 1) * SLOTH, c1h + (size_t)(j + 1) * SLOTH);
      signal_slot(fF + (size_t)(bid - 256) * 4, (unsigned)(j + 1));
    }
  }
}

// ---- attention phase (256 threads; R13/R15-proven code, explicit args) ----
__device__ __forceinline__ void attn_phase(
    int ab, int tq,
    const unsigned short* __restrict__ ak, const unsigned short* __restrict__ enc,
    const unsigned short* __restrict__ dh1, unsigned short* __restrict__ ctxb,
    float* qs, float* sc) {
  int tid = threadIdx.x;
  {
    ushort4 u4 = *(const ushort4*)(dh1 + (size_t)tq * SLOTH + (size_t)ab * 1024 + tid * 4);
    qs[tid * 4 + 0] = b2f(u4.x); qs[tid * 4 + 1] = b2f(u4.y);
    qs[tid * 4 + 2] = b2f(u4.z); qs[tid * 4 + 3] = b2f(u4.w);
  }
  __syncthreads();
  int w = tid >> 6, l = tid & 63;
  for (int ss = 0; ss < 16; ss++) {
    int s = w * 16 + ss;
    const unsigned short* kr = ak + (size_t)(s * 32 + ab) * 1024;
    float p = 0.f;
#pragma unroll
    for (int i = 0; i < 4; i++) {
      int e = (l + i * 64) * 4;
      ushort4 u4 = *(const ushort4*)&kr[e];
      p += qs[e] * b2f(u4.x) + qs[e + 1] * b2f(u4.y)
         + qs[e + 2] * b2f(u4.z) + qs[e + 3] * b2f(u4.w);
    }
    for (int off = 32; off; off >>= 1) p += __shfl_down(p, off);
    if (l == 0) sc[s] = p;
  }
  __syncthreads();
  if (tid < 64) {
    float v = sc[tid], m = v;
    for (int off = 32; off; off >>= 1) m = fmaxf(m, __shfl_xor(m, off));
    float e = expf(v - m), su = e;
    for (int off = 32; off; off >>= 1) su += __shfl_xor(su, off);
    sc[tid] = e / su;
  }
  __syncthreads();
  {
    int h4 = tid * 4;
    float a0 = 0.f, a1 = 0.f, a2 = 0.f, a3 = 0.f;
#pragma unroll 8
    for (int s = 0; s < 64; s++) {
      float p = sc[s];
      ushort4 u4 = *(const ushort4*)&enc[(size_t)(s * 32 + ab) * 1024 + h4];
      a0 += p * b2f(u4.x); a1 += p * b2f(u4.y);
      a2 += p * b2f(u4.z); a3 += p * b2f(u4.w);
    }
    unsigned* cp = (unsigned*)(ctxb + (size_t)tq * SLOTH) + ab * 512 + tid * 2;
    __hip_atomic_store(cp, (unsigned)f2b(a0) | ((unsigned)f2b(a1) << 16),
                       __ATOMIC_RELAXED, __HIP_MEMORY_SCOPE_AGENT);
    __hip_atomic_store(cp + 1, (unsigned)f2b(a2) | ((unsigned)f2b(a3) << 16),
                       __ATOMIC_RELAXED, __HIP_MEMORY_SCOPE_AGENT);
  }
  __syncthreads();
}

// ========== fused-cell persistent decoder: 256 blocks x 256 thr, 1/CU ======
// Block owns 16 gate-cols for BOTH cells. LDS 83200 B (> 80KB => HW enforces
// 1 block/CU; 256 blocks on 256 CUs, zero CU sharing). wD0c+wD1 in LDS;
// wDh0+wDh1 streamed from L2 (2MB/XCD resident, under R12 thrash threshold).
// Chain/step: wait fP -> cell0 -> sig fH0 -> wait fH0 -> cell1 -> sig fH1
//             -> [blocks 0-31: wait fH1 -> attn(t+1) -> sig fP].
// cell0's dh0(t)/dh1(t) dependencies are transitively covered by fP(t+1)
// (attn waited fH1(t), cell1(t-1) follows cell0(t-1) in-block).
// Slots: fH0=flags+0 (256), fH1=+1024 (256), fP=+2048 (32).
__global__ __launch_bounds__(256) void dec_persist(
    const unsigned short* __restrict__ ak, const unsigned short* __restrict__ enc,
    const float* __restrict__ gxd,
    const unsigned short* __restrict__ wDh0, const unsigned short* __restrict__ wD0c,
    const unsigned short* __restrict__ wD1, const unsigned short* __restrict__ wDh1,
    const float* __restrict__ db1, unsigned short* __restrict__ ctxb,
    unsigned short* __restrict__ dh0, float* __restrict__ dc0,
    unsigned short* __restrict__ dh1, float* __restrict__ dc1,
    unsigned* __restrict__ flags) {
  __shared__ unsigned short wl[2][16 * 1032];   // 66048 B: wD0c, wD1
  __shared__ float red[4][32][17];              // 8704 B
  __shared__ float qs[2048];                    // 8192 B (padded: LDS > 80KB)
  __shared__ float sc[64];                      // 256 B
  int bid = blockIdx.x, tid = threadIdx.x;
  int u0 = bid * 4;
  unsigned* fH0 = flags;
  unsigned* fH1 = flags + 1024;
  unsigned* fP  = flags + 2048;
  // ---- one-time LDS preload of wD0c, wD1 ----
  {
    for (int i = tid; i < 2048; i += 256) {
      int c = i >> 7, c8 = (i & 127) * 8;
      size_t grow = (size_t)(c >> 2) * 1024 + u0 + (c & 3);
      *(bs8*)&wl[0][c * 1032 + c8] = *(const bs8*)(wD0c + grow * 1024 + c8);
      *(bs8*)&wl[1][c * 1032 + c8] = *(const bs8*)(wD1 + grow * 1024 + c8);
    }
    __syncthreads();
  }
  // ---- bootstrap: ctx(0) from dh1(0) (init_dec, kernel boundary) ----
  if (bid < 32) {
    attn_phase(bid, 0, ak, enc, dh1, ctxb, qs, sc);
    signal_slot(fP + (size_t)bid * 4, 1u);
  }
  for (int t = 0; t < 64; t++) {
    // ---- cell0: h0 @ wDh0 (streamed) + ctx @ wD0c (LDS) + gxd ----
    waitN(fP, 32, (unsigned)(t + 1));                          // ctx(t) ready
    f32x4 a0 = {0.f, 0.f, 0.f, 0.f}, a1 = {0.f, 0.f, 0.f, 0.f};
    mfma_half_glb(dh0 + (size_t)t * SLOTH, wDh0, u0, a0, a1);
    mfma_half_lds(ctxb + (size_t)t * SLOTH, wl[0], a0, a1);
    red_write4(a0, a1, red);
    cell_finishN<4>(u0, red, gxd + (size_t)t * 131072, nullptr,
                    dc0 + (size_t)t * SLOTH,
                    dh0 + (size_t)(t + 1) * SLOTH, dc0 + (size_t)(t + 1) * SLOTH);
    signal_slot(fH0 + (size_t)bid * 4, (unsigned)(t + 1));
    // ---- cell1: h1 @ wDh1 (streamed) + h0' @ wD1 (LDS) + db1 ----
    waitN(fH0, 256, (unsigned)(t + 1));                        // dh0(t+1) ready
    f32x4 b0 = {0.f, 0.f, 0.f, 0.f}, b1 = {0.f, 0.f, 0.f, 0.f};
    mfma_half_glb(dh1 + (size_t)t * SLOTH, wDh1, u0, b0, b1);
    mfma_half_lds(dh0 + (size_t)(t + 1) * SLOTH, wl[1], b0, b1);
    red_write4(b0, b1, red);
    cell_finishN<4>(u0, red, nullptr, db1, dc1 + (size_t)t * SLOTH,
                    dh1 + (size_t)(t + 1) * SLOTH, dc1 + (size_t)(t + 1) * SLOTH);
    signal_slot(fH1 + (size_t)bid * 4, (unsigned)(t + 1));
    // ---- attention for step t+1 on blocks 0-31 ----
    if (bid < 32 && t < 63) {
      waitN(fH1, 256, (unsigned)(t + 1));                      // dh1(t+1) ready
      attn_phase(bid, t + 1, ak, enc, dh1, ctxb, qs, sc);
      signal_slot(fP + (size_t)bid * 4, (unsigned)(t + 2));
    }
  }
}

// ---- merged f32 -> bf16 weight conversion ---------------------------------
struct CvtDesc { const float* src; unsigned short* dst; int total8, cols, ld, col0, blk0; };
struct CvtArgs { CvtDesc d[11]; };
__global__ __launch_bounds__(256) void cvt_all(CvtArgs a) {
  int blk = blockIdx.x, seg = 0;
#pragma unroll
  for (int i = 1; i < 11; i++) if (blk >= a.d[i].blk0) seg = i;
  CvtDesc d = a.d[seg];
  int idx = (blk - d.blk0) * 256 + threadIdx.x;
  if (idx >= d.total8) return;
  int cpr = d.cols >> 3;
  int r = idx / cpr, c8 = (idx - r * cpr) * 8;
  const float* s = d.src + (size_t)r * d.ld + d.col0 + c8;
  float4 x = *(const float4*)s, y = *(const float4*)(s + 4);
  unsigned short o[8] = {f2b(x.x), f2b(x.y), f2b(x.z), f2b(x.w),
                         f2b(y.x), f2b(y.y), f2b(y.z), f2b(y.w)};
  *(bs8*)(d.dst + (size_t)r * d.cols + c8) = *(bs8*)o;
}

// ---- embedding gather -> bf16 ---------------------------------------------
__global__ __launch_bounds__(256) void embed_kernel(
    const int* __restrict__ src, const int* __restrict__ prev,
    const float* __restrict__ emb,
    unsigned short* __restrict__ se, unsigned short* __restrict__ te) {
  int idx = blockIdx.x * 256 + threadIdx.x;
  int half = idx >> 17;
  int r = (idx >> 6) & 2047, c8 = (idx & 63) * 8;
  int s = r >> 5, b = r & 31;
  const int* tok = half ? prev : src;
  unsigned short* dst = half ? te : se;
  int t = tok[b * 64 + s];
  const float* e = emb + (size_t)t * 512 + c8;
  float4 a = *(const float4*)e, bb = *(const float4*)(e + 4);
  unsigned short o[8] = {f2b(a.x), f2b(a.y), f2b(a.z), f2b(a.w),
                         f2b(bb.x), f2b(bb.y), f2b(bb.z), f2b(bb.w)};
  *(bs8*)(dst + (size_t)r * 512 + c8) = *(bs8*)o;
}

#define NFLAGS 6272
__global__ __launch_bounds__(256) void zero_init(
    unsigned short* y0h, unsigned short* y1h, float* c0h, float* c1h,
    unsigned* flags) {
  int i = blockIdx.x * 256 + threadIdx.x;
  y0h[i] = 0; y1h[i] = 0; c0h[i] = 0.f; c1h[i] = 0.f;
  if (i < NFLAGS) flags[i] = 0u;
}
__global__ __launch_bounds__(256) void init_dec(
    const unsigned short* __restrict__ y0f, const unsigned short* __restrict__ y1f,
    const float* __restrict__ c0f, const float* __restrict__ c1f,
    unsigned short* dh0, unsigned short* dh1, float* dc0, float* dc1) {
  int i = blockIdx.x * 256 + threadIdx.x;
  dh0[i] = y0f[i]; dh1[i] = y1f[i]; dc0[i] = c0f[i]; dc1[i] = c1f[i];
}

// ---- bf16 MFMA GEMM, global_load_lds + T2 XOR swizzle (+T1 for logits) ----
template <int OUTMODE>
__global__ __launch_bounds__(256) void gemm_bf16(
    const unsigned short* __restrict__ A, int lda,
    const unsigned short* __restrict__ B, int ldb,
    const float* __restrict__ bias, void* __restrict__ Cp, int ldc, int K) {
  __shared__ unsigned short As[128 * 64];
  __shared__ unsigned short Bs[128 * 64];
  int tid = threadIdx.x;
  int m0, n0;
  if (OUTMODE == 1) {
    int nwg = gridDim.x * gridDim.y;
    int orig = blockIdx.y * gridDim.x + blockIdx.x;
    int q = nwg >> 3;
    int wg = (orig & 7) * q + (orig >> 3);
    m0 = (wg % gridDim.x) * 128;
    n0 = (wg / gridDim.x) * 128;
  } else {
    m0 = blockIdx.x * 128; n0 = blockIdx.y * 128;
  }
  int w = tid >> 6, l = tid & 63;
  int wr = w >> 1, wc = w & 1;
  int swz = ((l & 7) * 8) ^ ((l >> 3) * 8);
  f32x4 acc[4][4];
#pragma unroll
  for (int i = 0; i < 4; i++)
#pragma unroll
    for (int j = 0; j < 4; j++)
#pragma unroll
      for (int r = 0; r < 4; r++) acc[i][j][r] = 0.f;

  for (int k0 = 0; k0 < K; k0 += 64) {
    __syncthreads();
#pragma unroll
    for (int i = 0; i < 4; i++) {
      int rb = w * 8 + i * 32;
      const unsigned short* ga = A + (size_t)(m0 + rb + (l >> 3)) * lda + k0 + swz;
      __builtin_amdgcn_global_load_lds((gbl_uint*)ga, (lds_uint*)&As[rb * 64], 16, 0, 0);
      const unsigned short* gb = B + (size_t)(n0 + rb + (l >> 3)) * ldb + k0 + swz;
      __builtin_amdgcn_global_load_lds((gbl_uint*)gb, (lds_uint*)&Bs[rb * 64], 16, 0, 0);
    }
    __syncthreads();
#pragma unroll
    for (int kk = 0; kk < 2; kk++) {
      bs8 af[4], bfr[4];
#pragma unroll
      for (int i = 0; i < 4; i++) {
        int R = wr * 64 + i * 16 + (l & 15);
        af[i] = *(const bs8*)&As[R * 64 + ((kk * 32 + (l >> 4) * 8) ^ ((R & 7) * 8))];
      }
#pragma unroll
      for (int j = 0; j < 4; j++) {
        int R = wc * 64 + j * 16 + (l & 15);
        bfr[j] = *(const bs8*)&Bs[R * 64 + ((kk * 32 + (l >> 4) * 8) ^ ((R & 7) * 8))];
      }
#pragma unroll
      for (int i = 0; i < 4; i++)
#pragma unroll
        for (int j = 0; j < 4; j++)
          acc[i][j] = mfma16(af[i], bfr[j], acc[i][j]);
    }
  }
#pragma unroll
  for (int i = 0; i < 4; i++) {
    int mrow = m0 + wr * 64 + i * 16 + (l >> 4) * 4;
#pragma unroll
    for (int j = 0; j < 4; j++) {
      int n = n0 + wc * 64 + j * 16 + (l & 15);
      float bb = bias ? bias[n] : 0.f;
#pragma unroll
      for (int r = 0; r < 4; r++) {
        int m = mrow + r;
        float v = acc[i][j][r] + bb;
        if (OUTMODE == 1)
          ((float*)Cp)[(size_t)(m & 31) * (64ull * NV) + (size_t)(m >> 5) * NV + n] = v;
        else if (OUTMODE == 2)
          ((unsigned short*)Cp)[(size_t)m * ldc + n] = f2b(v);
        else
          ((float*)Cp)[(size_t)m * ldc + n] = v;
      }
    }
  }
}

extern "C" void kernel_launch(void* const* d_in, const int* in_sizes, int n_in,
                              void* d_out, int out_size, void* d_ws, size_t ws_size,
                              hipStream_t stream) {
  (void)in_sizes; (void)n_in; (void)out_size; (void)ws_size;
  const int*   src   = (const int*)d_in[0];
  const int*   prev  = (const int*)d_in[1];
  const float* emb   = (const float*)d_in[2];
  const float* eWih0 = (const float*)d_in[3];
  const float* eWhh0 = (const float*)d_in[4];
  const float* eb0   = (const float*)d_in[5];
  const float* eWih1 = (const float*)d_in[6];
  const float* eWhh1 = (const float*)d_in[7];
  const float* eb1   = (const float*)d_in[8];
  const float* dWih0 = (const float*)d_in[9];
  const float* dWhh0 = (const float*)d_in[10];
  const float* db0   = (const float*)d_in[11];
  const float* dWih1 = (const float*)d_in[12];
  const float* dWhh1 = (const float*)d_in[13];
  const float* db1   = (const float*)d_in[14];
  const float* Wk    = (const float*)d_in[15];
  const float* bk    = (const float*)d_in[16];
  const float* Wh    = (const float*)d_in[17];
  const float* bh    = (const float*)d_in[18];
  float* out = (float*)d_out;

  char* p = (char*)d_ws;
  auto alloc = [&](size_t bytes) {
    char* r = p; p += (bytes + 255) & ~(size_t)255; return r;
  };
  float* gx0 = (float*)alloc(2048ull * 4096 * 4);
  float* gxd = (float*)alloc(2048ull * 4096 * 4);
  float* c0h = (float*)alloc(65ull * SLOTH * 4);
  float* c1h = (float*)alloc(65ull * SLOTH * 4);
  float* dc0 = (float*)alloc(65ull * SLOTH * 4);
  float* dc1 = (float*)alloc(65ull * SLOTH * 4);
  unsigned short* y0h  = (unsigned short*)alloc(65ull * SLOTH * 2);
  unsigned short* y1h  = (unsigned short*)alloc(65ull * SLOTH * 2);
  unsigned short* dh0  = (unsigned short*)alloc(65ull * SLOTH * 2);
  unsigned short* dh1  = (unsigned short*)alloc(65ull * SLOTH * 2);
  unsigned short* ctxb = (unsigned short*)alloc(65ull * SLOTH * 2);
  unsigned short* se   = (unsigned short*)alloc(2048ull * 512 * 2);
  unsigned short* te   = (unsigned short*)alloc(2048ull * 512 * 2);
  unsigned short* ak   = (unsigned short*)alloc(2048ull * 1024 * 2);
  unsigned short* wE0  = (unsigned short*)alloc(4096ull * 512 * 2);
  unsigned short* wH0  = (unsigned short*)alloc(4096ull * 1024 * 2);
  unsigned short* wE1  = (unsigned short*)alloc(4096ull * 1024 * 2);
  unsigned short* wH1  = (unsigned short*)alloc(4096ull * 1024 * 2);
  unsigned short* wD0x = (unsigned short*)alloc(4096ull * 512 * 2);
  unsigned short* wD0c = (unsigned short*)alloc(4096ull * 1024 * 2);
  unsigned short* wDh0 = (unsigned short*)alloc(4096ull * 1024 * 2);
  unsigned short* wD1  = (unsigned short*)alloc(4096ull * 1024 * 2);
  unsigned short* wDh1 = (unsigned short*)alloc(4096ull * 1024 * 2);
  unsigned short* wK   = (unsigned short*)alloc(1024ull * 1024 * 2);
  unsigned short* wV   = (unsigned short*)alloc((size_t)NV * 1024 * 2);
  unsigned* flags = (unsigned*)alloc((size_t)NFLAGS * 4);
  unsigned* fE = flags + 4224;
  unsigned* fF = flags + 5248;

  // merged weight conversions
  CvtArgs ca; int nb = 0, ci = 0;
  auto addcvt = [&](const float* s, unsigned short* d, int rows, int cols, int ld, int c0) {
    int t8 = rows * cols / 8;
    ca.d[ci++] = CvtDesc{s, d, t8, cols, ld, c0, nb};
    nb += (t8 + 255) / 256;
  };
  addcvt(eWih0, wE0, 4096, 512, 512, 0);
  addcvt(eWhh0, wH0, 4096, 1024, 1024, 0);
  addcvt(eWih1, wE1, 4096, 1024, 1024, 0);
  addcvt(eWhh1, wH1, 4096, 1024, 1024, 0);
  addcvt(dWih0, wD0x, 4096, 512, 1536, 0);
  addcvt(dWih0, wD0c, 4096, 1024, 1536, 512);
  addcvt(dWhh0, wDh0, 4096, 1024, 1024, 0);
  addcvt(dWih1, wD1, 4096, 1024, 1024, 0);
  addcvt(dWhh1, wDh1, 4096, 1024, 1024, 0);
  addcvt(Wk, wK, 1024, 1024, 1024, 0);
  addcvt(Wh, wV, NV, 1024, 1024, 0);
  cvt_all<<<nb, 256, 0, stream>>>(ca);

  zero_init<<<128, 256, 0, stream>>>(y0h, y1h, c0h, c1h, flags);
  embed_kernel<<<1024, 256, 0, stream>>>(src, prev, emb, se, te);

  // input-side gate GEMMs
  gemm_bf16<0><<<dim3(16, 32), 256, 0, stream>>>(se, 512, wE0, 512, eb0, gx0, 4096, 512);
  gemm_bf16<0><<<dim3(16, 32), 256, 0, stream>>>(te, 512, wD0x, 512, db0, gxd, 4096, 512);

  // persistent encoder (R15-proven)
  enc_persist<<<512, 256, 0, stream>>>(wH0, gx0, y0h, c0h, wE1, wH1, eb1,
                                       y1h, c1h, fE, fF);

  // attention keys
  gemm_bf16<2><<<dim3(16, 8), 256, 0, stream>>>(y1h + SLOTH, 1024, wK, 1024, bk, ak, 1024, 1024);
  // decoder initial states = encoder finals
  init_dec<<<128, 256, 0, stream>>>(y0h + 64 * SLOTH, y1h + 64 * SLOTH,
                                    c0h + 64 * SLOTH, c1h + 64 * SLOTH,
                                    dh0, dh1, dc0, dc1);
  // fused-cell persistent decoder: 256 blocks x 256 threads, 1 block/CU
  dec_persist<<<256, 256, 0, stream>>>(ak, y1h + SLOTH, gxd, wDh0, wD0c, wD1, wDh1,
                                       db1, ctxb, dh0, dc0, dh1, dc1, flags);
  // final logits
  gemm_bf16<1><<<dim3(16, 250), 256, 0, stream>>>(dh1 + SLOTH, 1024, wV, 1024, bh, out, NV, 1024);
}

// Round 19
// 2640.050 us; speedup vs baseline: 1.0180x; 1.0180x over previous
//
#include <hip/hip_runtime.h>
#include <cmath>

typedef short bs8 __attribute__((ext_vector_type(8)));
typedef float f32x4 __attribute__((ext_vector_type(4)));
typedef __attribute__((address_space(3))) unsigned lds_uint;
typedef __attribute__((address_space(1))) const unsigned gbl_uint;

#define NV 32000
#define SLOTH (32 * 1024)

__device__ __forceinline__ float b2f(unsigned short u) {
  union { unsigned int i; float f; } v; v.i = ((unsigned int)u) << 16; return v.f;
}
__device__ __forceinline__ unsigned short f2b(float f) {
  unsigned int u = __float_as_uint(f);
  return (unsigned short)((u + 0x7FFFu + ((u >> 16) & 1u)) >> 16);
}
__device__ __forceinline__ f32x4 mfma16(bs8 a, bs8 b, f32x4 c) {
  return __builtin_amdgcn_mfma_f32_16x16x32_bf16(a, b, c, 0, 0, 0);
}

// ---- per-producer step-valued flag slots (NO RMW; 16B-spaced) -------------
__device__ __forceinline__ void waitN(const unsigned* slots, int n, unsigned target) {
  if (threadIdx.x < 64) {
    for (;;) {
      unsigned mn = 0xffffffffu;
      for (int i = threadIdx.x; i < n; i += 64) {
        unsigned v = __hip_atomic_load(slots + (size_t)i * 4,
                                       __ATOMIC_RELAXED, __HIP_MEMORY_SCOPE_AGENT);
        mn = mn < v ? mn : v;
      }
#pragma unroll
      for (int off = 32; off; off >>= 1) {
        unsigned o = __shfl_xor(mn, off);
        mn = mn < o ? mn : o;
      }
      if (mn >= target) break;
      __builtin_amdgcn_s_sleep(2);
    }
  }
  __syncthreads();
}
__device__ __forceinline__ void signal_slot(unsigned* slot, unsigned val) {
  __syncthreads();   // full vmcnt drain: data stores globally visible first
  if (threadIdx.x == 0)
    __hip_atomic_store(slot, val, __ATOMIC_RELAXED, __HIP_MEMORY_SCOPE_AGENT);
}

// ---- 4-wave LDS-weight MFMA (R12/R13-proven) ------------------------------
__device__ __forceinline__ void mfma_half_lds(
    const unsigned short* __restrict__ A, const unsigned short* wl,
    f32x4& acc0, f32x4& acc1) {
  int tid = threadIdx.x;
  int w = tid >> 6, l = tid & 63;
  int col = l & 15;
  int kb = w * 256 + (l >> 4) * 8;
  const unsigned short* ap = A + (size_t)col * 1024 + kb;
  const unsigned short* wp = wl + col * 1032 + kb;
#pragma unroll
  for (int kk = 0; kk < 256; kk += 32) {
    bs8 b1 = *(const bs8*)(wp + kk);
    acc0 = mfma16(*(const bs8*)(ap + kk), b1, acc0);
    acc1 = mfma16(*(const bs8*)(ap + 16 * 1024 + kk), b1, acc1);
  }
}
__device__ __forceinline__ void red_write4(f32x4 acc0, f32x4 acc1, float (*red)[32][17]) {
  int tid = threadIdx.x;
  int w = tid >> 6, l = tid & 63, col = l & 15;
#pragma unroll
  for (int r = 0; r < 4; r++) {
    red[w][(l >> 4) * 4 + r][col] = acc0[r];
    red[w][16 + (l >> 4) * 4 + r][col] = acc1[r];
  }
  __syncthreads();
}
// ---- cell finish with EARLY SIGNAL: h-stores drain before the slot store; -
// ---- block-private c-state stores issue AFTER the signal (off the chain). -
__device__ __forceinline__ void cell_finishS(
    int u0, float (*red)[32][17],
    const float* __restrict__ gxrow, const float* __restrict__ bias,
    const float* __restrict__ cprev,
    unsigned short* __restrict__ hout, float* __restrict__ cout,
    unsigned* __restrict__ slot, unsigned val) {
  int tid = threadIdx.x;
  float cn = 0.f;
  int b_ = tid >> 2, ul = tid & 3, u = u0 + ul;
  if (tid < 128) {
    float s0 = 0.f, s1 = 0.f, s2 = 0.f, s3 = 0.f;
#pragma unroll
    for (int ww = 0; ww < 4; ww++) {
      s0 += red[ww][b_][ul];      s1 += red[ww][b_][4 + ul];
      s2 += red[ww][b_][8 + ul];  s3 += red[ww][b_][12 + ul];
    }
    if (gxrow) {
      const float* gp = gxrow + (size_t)b_ * 4096 + u;
      s0 += gp[0]; s1 += gp[1024]; s2 += gp[2048]; s3 += gp[3072];
    }
    if (bias) {
      s0 += bias[u]; s1 += bias[u + 1024]; s2 += bias[u + 2048]; s3 += bias[u + 3072];
    }
    float si = 1.f / (1.f + expf(-s0));
    float sf = 1.f / (1.f + expf(-s1));
    float tg = tanhf(s2);
    float so = 1.f / (1.f + expf(-s3));
    cn = sf * cprev[b_ * 1024 + u] + si * tg;
    float hn = so * tanhf(cn);
    unsigned hv = (unsigned)f2b(hn);
    unsigned ho = __shfl_down(hv, 1);
    if (!(ul & 1)) {
      unsigned packed = hv | (ho << 16);
      __hip_atomic_store((unsigned*)hout + ((size_t)b_ * 512 + (u0 >> 1) + (ul >> 1)),
                         packed, __ATOMIC_RELAXED, __HIP_MEMORY_SCOPE_AGENT);
    }
  }
  __syncthreads();   // drains h atomic stores (and earlier phases)
  if (tid == 0)
    __hip_atomic_store(slot, val, __ATOMIC_RELAXED, __HIP_MEMORY_SCOPE_AGENT);
  if (tid < 128)
    cout[b_ * 1024 + u] = cn;   // block-private; off the dependency chain
}

// ================= persistent encoder (R15 structure + early signal) =======
__global__ __launch_bounds__(256, 2) void enc_persist(
    const unsigned short* __restrict__ wH0, const float* __restrict__ gx0,
    unsigned short* __restrict__ y0h, float* __restrict__ c0h,
    const unsigned short* __restrict__ wE1, const unsigned short* __restrict__ wH1,
    const float* __restrict__ eb1,
    unsigned short* __restrict__ y1h, float* __restrict__ c1h,
    unsigned* __restrict__ fE, unsigned* __restrict__ fF) {
  __shared__ unsigned short wl[2][16 * 1032];
  __shared__ float red[4][32][17];
  int bid = blockIdx.x, tid = threadIdx.x;
  int lay0 = (bid < 256);
  int u0 = (bid & 255) * 4;
  {
    const unsigned short* W0 = lay0 ? wH0 : wE1;
    const unsigned short* W1 = lay0 ? wH0 : wH1;
    for (int i = tid; i < 2048; i += 256) {
      int c = i >> 7, c8 = (i & 127) * 8;
      size_t grow = (size_t)(c >> 2) * 1024 + u0 + (c & 3);
      *(bs8*)&wl[0][c * 1032 + c8] = *(const bs8*)(W0 + grow * 1024 + c8);
      *(bs8*)&wl[1][c * 1032 + c8] = *(const bs8*)(W1 + grow * 1024 + c8);
    }
    __syncthreads();
  }
  if (lay0) {
    for (int d = 0; d < 64; d++) {
      if (d > 0) waitN(fE, 256, (unsigned)d);
      f32x4 a0 = {0.f, 0.f, 0.f, 0.f}, a1 = {0.f, 0.f, 0.f, 0.f};
      mfma_half_lds(y0h + (size_t)d * SLOTH, wl[0], a0, a1);
      red_write4(a0, a1, red);
      cell_finishS(u0, red, gx0 + (size_t)d * 131072, nullptr,
                   c0h + (size_t)d * SLOTH,
                   y0h + (size_t)(d + 1) * SLOTH, c0h + (size_t)(d + 1) * SLOTH,
                   fE + (size_t)bid * 4, (unsigned)(d + 1));
    }
  } else {
    for (int j = 0; j < 64; j++) {
      waitN(fE, 256, (unsigned)(j + 1));
      if (j > 0) waitN(fF, 256, (unsigned)j);
      f32x4 a0 = {0.f, 0.f, 0.f, 0.f}, a1 = {0.f, 0.f, 0.f, 0.f};
      mfma_half_lds(y0h + (size_t)(j + 1) * SLOTH, wl[0], a0, a1);
      mfma_half_lds(y1h + (size_t)j * SLOTH, wl[1], a0, a1);
      red_write4(a0, a1, red);
      cell_finishS(u0, red, nullptr, eb1, c1h + (size_t)j * SLOTH,
                   y1h + (size_t)(j + 1) * SLOTH, c1h + (size_t)(j + 1) * SLOTH,
                   fF + (size_t)(bid - 256) * 4, (unsigned)(j + 1));
    }
  }
}

// ========= persistent decoder (R13 structure + early signal) ===============
// Slots (words, 16B-spaced): fH0=+0, fH1=+1024, fP=+2048.
__global__ __launch_bounds__(256, 2) void dec_persist(
    const unsigned short* __restrict__ ak, const unsigned short* __restrict__ enc,
    const float* __restrict__ gxd,
    const unsigned short* __restrict__ wDh0, const unsigned short* __restrict__ wD0c,
    const unsigned short* __restrict__ wD1, const unsigned short* __restrict__ wDh1,
    const float* __restrict__ db1, unsigned short* __restrict__ ctxb,
    unsigned short* __restrict__ dh0, float* __restrict__ dc0,
    unsigned short* __restrict__ dh1, float* __restrict__ dc1,
    unsigned* __restrict__ flags) {
  __shared__ unsigned short wl[2][16 * 1032];
  __shared__ float red[4][32][17];
  __shared__ float qs[1024];
  __shared__ float sc[64];
  int bid = blockIdx.x, tid = threadIdx.x;
  int cell0 = (bid < 256);
  int u0 = (bid & 255) * 4;
  unsigned* fH0 = flags;
  unsigned* fH1 = flags + 1024;
  unsigned* fP  = flags + 2048;
  {
    const unsigned short* W0 = cell0 ? wDh0 : wD1;
    const unsigned short* W1 = cell0 ? wD0c : wDh1;
    for (int i = tid; i < 2048; i += 256) {
      int c = i >> 7, c8 = (i & 127) * 8;
      size_t grow = (size_t)(c >> 2) * 1024 + u0 + (c & 3);
      *(bs8*)&wl[0][c * 1032 + c8] = *(const bs8*)(W0 + grow * 1024 + c8);
      *(bs8*)&wl[1][c * 1032 + c8] = *(const bs8*)(W1 + grow * 1024 + c8);
    }
    __syncthreads();
  }
  if (cell0) {
    for (int t = 0; t < 64; t++) {
      if (t > 0) waitN(fH0, 256, (unsigned)t);                 // dh0(t) ready
      f32x4 a0 = {0.f, 0.f, 0.f, 0.f}, a1 = {0.f, 0.f, 0.f, 0.f};
      mfma_half_lds(dh0 + (size_t)t * SLOTH, wl[0], a0, a1);   // h0 @ wDh0
      waitN(fP, 32, (unsigned)(t + 1));                        // ctx(t) ready
      mfma_half_lds(ctxb + (size_t)t * SLOTH, wl[1], a0, a1);  // ctx @ wD0c
      red_write4(a0, a1, red);
      cell_finishS(u0, red, gxd + (size_t)t * 131072, nullptr,
                   dc0 + (size_t)t * SLOTH,
                   dh0 + (size_t)(t + 1) * SLOTH, dc0 + (size_t)(t + 1) * SLOTH,
                   fH0 + (size_t)bid * 4, (unsigned)(t + 1));
    }
  } else {
    int ab = bid - 256;
    for (int t = 0; t < 64; t++) {
      if (t > 0) waitN(fH1, 256, (unsigned)t);                 // dh1(t) ready
      if (ab < 32) {
        {
          ushort4 u4 = *(const ushort4*)(dh1 + (size_t)t * SLOTH + (size_t)ab * 1024 + tid * 4);
          qs[tid * 4 + 0] = b2f(u4.x); qs[tid * 4 + 1] = b2f(u4.y);
          qs[tid * 4 + 2] = b2f(u4.z); qs[tid * 4 + 3] = b2f(u4.w);
        }
        __syncthreads();
        int w = tid >> 6, l = tid & 63;
        for (int ss = 0; ss < 16; ss++) {
          int s = w * 16 + ss;
          const unsigned short* kr = ak + (size_t)(s * 32 + ab) * 1024;
          float p = 0.f;
#pragma unroll
          for (int i = 0; i < 4; i++) {
            int e = (l + i * 64) * 4;
            ushort4 u4 = *(const ushort4*)&kr[e];
            p += qs[e] * b2f(u4.x) + qs[e + 1] * b2f(u4.y)
               + qs[e + 2] * b2f(u4.z) + qs[e + 3] * b2f(u4.w);
          }
          for (int off = 32; off; off >>= 1) p += __shfl_down(p, off);
          if (l == 0) sc[s] = p;
        }
        __syncthreads();
        if (tid < 64) {
          float v = sc[tid], m = v;
          for (int off = 32; off; off >>= 1) m = fmaxf(m, __shfl_xor(m, off));
          float e = expf(v - m), su = e;
          for (int off = 32; off; off >>= 1) su += __shfl_xor(su, off);
          sc[tid] = e / su;
        }
        __syncthreads();
        {
          int h4 = tid * 4;
          float a0 = 0.f, a1 = 0.f, a2 = 0.f, a3 = 0.f;
#pragma unroll 8
          for (int s = 0; s < 64; s++) {
            float p = sc[s];
            ushort4 u4 = *(const ushort4*)&enc[(size_t)(s * 32 + ab) * 1024 + h4];
            a0 += p * b2f(u4.x); a1 += p * b2f(u4.y);
            a2 += p * b2f(u4.z); a3 += p * b2f(u4.w);
          }
          unsigned* cp = (unsigned*)(ctxb + (size_t)t * SLOTH) + ab * 512 + tid * 2;
          __hip_atomic_store(cp, (unsigned)f2b(a0) | ((unsigned)f2b(a1) << 16),
                             __ATOMIC_RELAXED, __HIP_MEMORY_SCOPE_AGENT);
          __hip_atomic_store(cp + 1, (unsigned)f2b(a2) | ((unsigned)f2b(a3) << 16),
                             __ATOMIC_RELAXED, __HIP_MEMORY_SCOPE_AGENT);
        }
        signal_slot(fP + (size_t)ab * 4, (unsigned)(t + 1));
      }
      f32x4 a0 = {0.f, 0.f, 0.f, 0.f}, a1 = {0.f, 0.f, 0.f, 0.f};
      mfma_half_lds(dh1 + (size_t)t * SLOTH, wl[1], a0, a1);   // h1 @ wDh1
      waitN(fH0, 256, (unsigned)(t + 1));                      // dh0(t+1) ready
      mfma_half_lds(dh0 + (size_t)(t + 1) * SLOTH, wl[0], a0, a1);  // h0' @ wD1
      red_write4(a0, a1, red);
      cell_finishS(u0, red, nullptr, db1, dc1 + (size_t)t * SLOTH,
                   dh1 + (size_t)(t + 1) * SLOTH, dc1 + (size_t)(t + 1) * SLOTH,
                   fH1 + (size_t)(bid - 256) * 4, (unsigned)(t + 1));
    }
  }
}

// ---- merged f32 -> bf16 weight conversion ---------------------------------
struct CvtDesc { const float* src; unsigned short* dst; int total8, cols, ld, col0, blk0; };
struct CvtArgs { CvtDesc d[11]; };
__global__ __launch_bounds__(256) void cvt_all(CvtArgs a) {
  int blk = blockIdx.x, seg = 0;
#pragma unroll
  for (int i = 1; i < 11; i++) if (blk >= a.d[i].blk0) seg = i;
  CvtDesc d = a.d[seg];
  int idx = (blk - d.blk0) * 256 + threadIdx.x;
  if (idx >= d.total8) return;
  int cpr = d.cols >> 3;
  int r = idx / cpr, c8 = (idx - r * cpr) * 8;
  const float* s = d.src + (size_t)r * d.ld + d.col0 + c8;
  float4 x = *(const float4*)s, y = *(const float4*)(s + 4);
  unsigned short o[8] = {f2b(x.x), f2b(x.y), f2b(x.z), f2b(x.w),
                         f2b(y.x), f2b(y.y), f2b(y.z), f2b(y.w)};
  *(bs8*)(d.dst + (size_t)r * d.cols + c8) = *(bs8*)o;
}

// ---- embedding gather -> bf16 ---------------------------------------------
__global__ __launch_bounds__(256) void embed_kernel(
    const int* __restrict__ src, const int* __restrict__ prev,
    const float* __restrict__ emb,
    unsigned short* __restrict__ se, unsigned short* __restrict__ te) {
  int idx = blockIdx.x * 256 + threadIdx.x;
  int half = idx >> 17;
  int r = (idx >> 6) & 2047, c8 = (idx & 63) * 8;
  int s = r >> 5, b = r & 31;
  const int* tok = half ? prev : src;
  unsigned short* dst = half ? te : se;
  int t = tok[b * 64 + s];
  const float* e = emb + (size_t)t * 512 + c8;
  float4 a = *(const float4*)e, bb = *(const float4*)(e + 4);
  unsigned short o[8] = {f2b(a.x), f2b(a.y), f2b(a.z), f2b(a.w),
                         f2b(bb.x), f2b(bb.y), f2b(bb.z), f2b(bb.w)};
  *(bs8*)(dst + (size_t)r * 512 + c8) = *(bs8*)o;
}

#define NFLAGS 6272
__global__ __launch_bounds__(256) void zero_init(
    unsigned short* y0h, unsigned short* y1h, float* c0h, float* c1h,
    unsigned* flags) {
  int i = blockIdx.x * 256 + threadIdx.x;
  y0h[i] = 0; y1h[i] = 0; c0h[i] = 0.f; c1h[i] = 0.f;
  if (i < NFLAGS) flags[i] = 0u;
}
__global__ __launch_bounds__(256) void init_dec(
    const unsigned short* __restrict__ y0f, const unsigned short* __restrict__ y1f,
    const float* __restrict__ c0f, const float* __restrict__ c1f,
    unsigned short* dh0, unsigned short* dh1, float* dc0, float* dc1) {
  int i = blockIdx.x * 256 + threadIdx.x;
  dh0[i] = y0f[i]; dh1[i] = y1f[i]; dc0[i] = c0f[i]; dc1[i] = c1f[i];
}

// ---- bf16 MFMA GEMM, global_load_lds + T2 XOR swizzle (+T1 for logits) ----
template <int OUTMODE>
__global__ __launch_bounds__(256) void gemm_bf16(
    const unsigned short* __restrict__ A, int lda,
    const unsigned short* __restrict__ B, int ldb,
    const float* __restrict__ bias, void* __restrict__ Cp, int ldc, int K) {
  __shared__ unsigned short As[128 * 64];
  __shared__ unsigned short Bs[128 * 64];
  int tid = threadIdx.x;
  int m0, n0;
  if (OUTMODE == 1) {
    int nwg = gridDim.x * gridDim.y;
    int orig = blockIdx.y * gridDim.x + blockIdx.x;
    int q = nwg >> 3;
    int wg = (orig & 7) * q + (orig >> 3);
    m0 = (wg % gridDim.x) * 128;
    n0 = (wg / gridDim.x) * 128;
  } else {
    m0 = blockIdx.x * 128; n0 = blockIdx.y * 128;
  }
  int w = tid >> 6, l = tid & 63;
  int wr = w >> 1, wc = w & 1;
  int swz = ((l & 7) * 8) ^ ((l >> 3) * 8);
  f32x4 acc[4][4];
#pragma unroll
  for (int i = 0; i < 4; i++)
#pragma unroll
    for (int j = 0; j < 4; j++)
#pragma unroll
      for (int r = 0; r < 4; r++) acc[i][j][r] = 0.f;

  for (int k0 = 0; k0 < K; k0 += 64) {
    __syncthreads();
#pragma unroll
    for (int i = 0; i < 4; i++) {
      int rb = w * 8 + i * 32;
      const unsigned short* ga = A + (size_t)(m0 + rb + (l >> 3)) * lda + k0 + swz;
      __builtin_amdgcn_global_load_lds((gbl_uint*)ga, (lds_uint*)&As[rb * 64], 16, 0, 0);
      const unsigned short* gb = B + (size_t)(n0 + rb + (l >> 3)) * ldb + k0 + swz;
      __builtin_amdgcn_global_load_lds((gbl_uint*)gb, (lds_uint*)&Bs[rb * 64], 16, 0, 0);
    }
    __syncthreads();
#pragma unroll
    for (int kk = 0; kk < 2; kk++) {
      bs8 af[4], bfr[4];
#pragma unroll
      for (int i = 0; i < 4; i++) {
        int R = wr * 64 + i * 16 + (l & 15);
        af[i] = *(const bs8*)&As[R * 64 + ((kk * 32 + (l >> 4) * 8) ^ ((R & 7) * 8))];
      }
#pragma unroll
      for (int j = 0; j < 4; j++) {
        int R = wc * 64 + j * 16 + (l & 15);
        bfr[j] = *(const bs8*)&Bs[R * 64 + ((kk * 32 + (l >> 4) * 8) ^ ((R & 7) * 8))];
      }
#pragma unroll
      for (int i = 0; i < 4; i++)
#pragma unroll
        for (int j = 0; j < 4; j++)
          acc[i][j] = mfma16(af[i], bfr[j], acc[i][j]);
    }
  }
#pragma unroll
  for (int i = 0; i < 4; i++) {
    int mrow = m0 + wr * 64 + i * 16 + (l >> 4) * 4;
#pragma unroll
    for (int j = 0; j < 4; j++) {
      int n = n0 + wc * 64 + j * 16 + (l & 15);
      float bb = bias ? bias[n] : 0.f;
#pragma unroll
      for (int r = 0; r < 4; r++) {
        int m = mrow + r;
        float v = acc[i][j][r] + bb;
        if (OUTMODE == 1)
          ((float*)Cp)[(size_t)(m & 31) * (64ull * NV) + (size_t)(m >> 5) * NV + n] = v;
        else if (OUTMODE == 2)
          ((unsigned short*)Cp)[(size_t)m * ldc + n] = f2b(v);
        else
          ((float*)Cp)[(size_t)m * ldc + n] = v;
      }
    }
  }
}

extern "C" void kernel_launch(void* const* d_in, const int* in_sizes, int n_in,
                              void* d_out, int out_size, void* d_ws, size_t ws_size,
                              hipStream_t stream) {
  (void)in_sizes; (void)n_in; (void)out_size; (void)ws_size;
  const int*   src   = (const int*)d_in[0];
  const int*   prev  = (const int*)d_in[1];
  const float* emb   = (const float*)d_in[2];
  const float* eWih0 = (const float*)d_in[3];
  const float* eWhh0 = (const float*)d_in[4];
  const float* eb0   = (const float*)d_in[5];
  const float* eWih1 = (const float*)d_in[6];
  const float* eWhh1 = (const float*)d_in[7];
  const float* eb1   = (const float*)d_in[8];
  const float* dWih0 = (const float*)d_in[9];
  const float* dWhh0 = (const float*)d_in[10];
  const float* db0   = (const float*)d_in[11];
  const float* dWih1 = (const float*)d_in[12];
  const float* dWhh1 = (const float*)d_in[13];
  const float* db1   = (const float*)d_in[14];
  const float* Wk    = (const float*)d_in[15];
  const float* bk    = (const float*)d_in[16];
  const float* Wh    = (const float*)d_in[17];
  const float* bh    = (const float*)d_in[18];
  float* out = (float*)d_out;

  char* p = (char*)d_ws;
  auto alloc = [&](size_t bytes) {
    char* r = p; p += (bytes + 255) & ~(size_t)255; return r;
  };
  float* gx0 = (float*)alloc(2048ull * 4096 * 4);
  float* gxd = (float*)alloc(2048ull * 4096 * 4);
  float* c0h = (float*)alloc(65ull * SLOTH * 4);
  float* c1h = (float*)alloc(65ull * SLOTH * 4);
  float* dc0 = (float*)alloc(65ull * SLOTH * 4);
  float* dc1 = (float*)alloc(65ull * SLOTH * 4);
  unsigned short* y0h  = (unsigned short*)alloc(65ull * SLOTH * 2);
  unsigned short* y1h  = (unsigned short*)alloc(65ull * SLOTH * 2);
  unsigned short* dh0  = (unsigned short*)alloc(65ull * SLOTH * 2);
  unsigned short* dh1  = (unsigned short*)alloc(65ull * SLOTH * 2);
  unsigned short* ctxb = (unsigned short*)alloc(65ull * SLOTH * 2);
  unsigned short* se   = (unsigned short*)alloc(2048ull * 512 * 2);
  unsigned short* te   = (unsigned short*)alloc(2048ull * 512 * 2);
  unsigned short* ak   = (unsigned short*)alloc(2048ull * 1024 * 2);
  unsigned short* wE0  = (unsigned short*)alloc(4096ull * 512 * 2);
  unsigned short* wH0  = (unsigned short*)alloc(4096ull * 1024 * 2);
  unsigned short* wE1  = (unsigned short*)alloc(4096ull * 1024 * 2);
  unsigned short* wH1  = (unsigned short*)alloc(4096ull * 1024 * 2);
  unsigned short* wD0x = (unsigned short*)alloc(4096ull * 512 * 2);
  unsigned short* wD0c = (unsigned short*)alloc(4096ull * 1024 * 2);
  unsigned short* wDh0 = (unsigned short*)alloc(4096ull * 1024 * 2);
  unsigned short* wD1  = (unsigned short*)alloc(4096ull * 1024 * 2);
  unsigned short* wDh1 = (unsigned short*)alloc(4096ull * 1024 * 2);
  unsigned short* wK   = (unsigned short*)alloc(1024ull * 1024 * 2);
  unsigned short* wV   = (unsigned short*)alloc((size_t)NV * 1024 * 2);
  unsigned* flags = (unsigned*)alloc((size_t)NFLAGS * 4);
  unsigned* fE = flags + 4224;
  unsigned* fF = flags + 5248;

  // merged weight conversions
  CvtArgs ca; int nb = 0, ci = 0;
  auto addcvt = [&](const float* s, unsigned short* d, int rows, int cols, int ld, int c0) {
    int t8 = rows * cols / 8;
    ca.d[ci++] = CvtDesc{s, d, t8, cols, ld, c0, nb};
    nb += (t8 + 255) / 256;
  };
  addcvt(eWih0, wE0, 4096, 512, 512, 0);
  addcvt(eWhh0, wH0, 4096, 1024, 1024, 0);
  addcvt(eWih1, wE1, 4096, 1024, 1024, 0);
  addcvt(eWhh1, wH1, 4096, 1024, 1024, 0);
  addcvt(dWih0, wD0x, 4096, 512, 1536, 0);
  addcvt(dWih0, wD0c, 4096, 1024, 1536, 512);
  addcvt(dWhh0, wDh0, 4096, 1024, 1024, 0);
  addcvt(dWih1, wD1, 4096, 1024, 1024, 0);
  addcvt(dWhh1, wDh1, 4096, 1024, 1024, 0);
  addcvt(Wk, wK, 1024, 1024, 1024, 0);
  addcvt(Wh, wV, NV, 1024, 1024, 0);
  cvt_all<<<nb, 256, 0, stream>>>(ca);

  zero_init<<<128, 256, 0, stream>>>(y0h, y1h, c0h, c1h, flags);
  embed_kernel<<<1024, 256, 0, stream>>>(src, prev, emb, se, te);

  // input-side gate GEMMs
  gemm_bf16<0><<<dim3(16, 32), 256, 0, stream>>>(se, 512, wE0, 512, eb0, gx0, 4096, 512);
  gemm_bf16<0><<<dim3(16, 32), 256, 0, stream>>>(te, 512, wD0x, 512, db0, gxd, 4096, 512);

  // persistent encoder
  enc_persist<<<512, 256, 0, stream>>>(wH0, gx0, y0h, c0h, wE1, wH1, eb1,
                                       y1h, c1h, fE, fF);

  // attention keys
  gemm_bf16<2><<<dim3(16, 8), 256, 0, stream>>>(y1h + SLOTH, 1024, wK, 1024, bk, ak, 1024, 1024);
  // decoder initial states = encoder finals
  init_dec<<<128, 256, 0, stream>>>(y0h + 64 * SLOTH, y1h + 64 * SLOTH,
                                    c0h + 64 * SLOTH, c1h + 64 * SLOTH,
                                    dh0, dh1, dc0, dc1);
  // persistent decoder (R13 structure, early-signal finish)
  dec_persist<<<512, 256, 0, stream>>>(ak, y1h + SLOTH, gxd, wDh0, wD0c, wD1, wDh1,
                                       db1, ctxb, dh0, dc0, dh1, dc1, flags);
  // final logits
  gemm_bf16<1><<<dim3(16, 250), 256, 0, stream>>>(dh1 + SLOTH, 1024, wV, 1024, bh, out, NV, 1024);
}